// Round 1
// 1318.152 us; speedup vs baseline: 1.0956x; 1.0956x over previous
//
#include <hip/hip_runtime.h>
#include <hip/hip_bf16.h>

#define B_ 4
#define H_ 16
#define S_ 2048
#define D_ 64

#define NTILE (S_ / 64)            // 32 k-tiles per head
#define TILE_SH (64 * 64)          // shorts per staged tile (8 KB)
#define HEAD_SH (NTILE * TILE_SH)  // shorts per head in scratch
#define NHEAD (B_ * H_)

// legacy-path LDS strides (fallback kernel only)
#define KS 72
#define PS 72

typedef __attribute__((ext_vector_type(8))) short bf16x8;
typedef __attribute__((ext_vector_type(4))) float f32x4;

__device__ __forceinline__ short f2bf(float x) {
    union { __hip_bfloat16 h; short s; } u;
    u.h = __float2bfloat16(x);
    return u.s;
}

typedef const __attribute__((address_space(1))) void GVp;
typedef __attribute__((address_space(3))) void LVp;

// 16B-wide async global->LDS. LDS dest = wave-uniform base + lane*16.
__device__ __forceinline__ void gll16(const void* g, void* l) {
    __builtin_amdgcn_global_load_lds((GVp*)g, (LVp*)l, 16, 0, 0);
}

// ======================= prep: K->bf16, V->V^T bf16, swizzled tiles ==========
// K scratch: per head, per 64-key tile, [row=key%64][dchunk] with
//   short offset = row*64 + ((dc*8) ^ ((row&7)*8))     (16B-chunk XOR swizzle)
// V scratch: transposed, [row=d][keychunk] with the same swizzle.
__global__ __launch_bounds__(256)
void prep_kernel(const float* __restrict__ K, const float* __restrict__ V,
                 short* __restrict__ kscr, short* __restrict__ vscr)
{
    const int gid = blockIdx.x * 256 + threadIdx.x;
    const int NK = NHEAD * S_ * (D_ / 8);   // 1,048,576 16B chunks
    if (gid < NK) {
        const int dc  = gid & 7;
        const int key = (gid >> 3) & (S_ - 1);
        const int bh  = gid >> 14;
        const float* src = K + ((size_t)bh * S_ + key) * D_ + dc * 8;
        bf16x8 v;
        #pragma unroll
        for (int j = 0; j < 8; ++j) v[j] = f2bf(src[j]);
        const int kt = key >> 6, row = key & 63;
        short* dst = kscr + (size_t)bh * HEAD_SH + (size_t)kt * TILE_SH
                   + row * 64 + ((dc * 8) ^ ((row & 7) * 8));
        *(bf16x8*)dst = v;
    } else {
        const int g  = gid - NK;
        const int d  = g & 63;
        const int kc = (g >> 6) & 7;
        const int kt = (g >> 9) & 31;
        const int bh = g >> 14;
        const float* src = V + ((size_t)bh * S_ + kt * 64 + kc * 8) * D_ + d;
        bf16x8 v;
        #pragma unroll
        for (int j = 0; j < 8; ++j) v[j] = f2bf(src[j * D_]);  // gather: coalesced across d
        short* dst = vscr + (size_t)bh * HEAD_SH + (size_t)kt * TILE_SH
                   + d * 64 + ((kc * 8) ^ ((d & 7) * 8));
        *(bf16x8*)dst = v;
    }
}

// ============================== main attention ===============================
__global__ __launch_bounds__(256, 4)
void attn2_kernel(const float* __restrict__ Q, const int* __restrict__ mask,
                  const short* __restrict__ kscr, const short* __restrict__ vscr,
                  float* __restrict__ out, float* __restrict__ wout)
{
    __shared__ __align__(16) short Ksh[TILE_SH];      // swizzled [key][d] bf16
    __shared__ __align__(16) short Vsh[TILE_SH];      // swizzled [d][key] bf16
    __shared__ __align__(16) float Pf[4][16 * 68];    // per-wave P fp32, padded pitch
    __shared__ int msh[64];

    const int tid  = threadIdx.x;
    const int wave = tid >> 6;
    const int lane = tid & 63;
    const int quad = lane >> 4;
    const int col  = lane & 15;

    const int bh = blockIdx.x >> 5;       // head 0..63
    const int qt = blockIdx.x & 31;       // q-tile within head
    const int q0 = qt * 64 + wave * 16;   // this wave's first q row

    const float* Qh = Q + (size_t)bh * S_ * D_;
    const int*   mk = mask + (size_t)(bh >> 4) * S_;
    const short* kb_head = kscr + (size_t)bh * HEAD_SH;
    const short* vb_head = vscr + (size_t)bh * HEAD_SH;
    float* outh = out  + (size_t)bh * S_ * D_;
    float* wh   = wout + (size_t)bh * S_ * S_;

    // ---- Q fragments (A-layout: m=col, k=quad*8+j), resident all kernel ----
    bf16x8 qf[2];
    {
        const float4* qp4 = (const float4*)(Qh + (size_t)(q0 + col) * D_ + quad * 8);
        float4 a = qp4[0], b = qp4[1], c = qp4[8], d = qp4[9];
        bf16x8 t0, t1;
        t0[0]=f2bf(a.x); t0[1]=f2bf(a.y); t0[2]=f2bf(a.z); t0[3]=f2bf(a.w);
        t0[4]=f2bf(b.x); t0[5]=f2bf(b.y); t0[6]=f2bf(b.z); t0[7]=f2bf(b.w);
        t1[0]=f2bf(c.x); t1[1]=f2bf(c.y); t1[2]=f2bf(c.z); t1[3]=f2bf(c.w);
        t1[4]=f2bf(d.x); t1[5]=f2bf(d.y); t1[6]=f2bf(d.z); t1[7]=f2bf(d.w);
        qf[0] = t0; qf[1] = t1;
    }

    // =========================== PASS 1: rowsums ===========================
    float rsum[4] = {0.f, 0.f, 0.f, 0.f};
    for (int tt = 0; tt < NTILE; ++tt) {
        __syncthreads();
        const short* ks = kb_head + (size_t)tt * TILE_SH;
        gll16(ks + tid * 8,        &Ksh[wave * 512]);
        gll16(ks + 2048 + tid * 8, &Ksh[2048 + wave * 512]);
        if (tid < 64) msh[tid] = mk[tt * 64 + tid];
        __syncthreads();
        #pragma unroll
        for (int sub = 0; sub < 4; ++sub) {
            const int row = sub * 16 + col;
            const short* kb = &Ksh[row * 64];
            const int sw = (row & 7) * 8;
            bf16x8 kf0 = *(const bf16x8*)&kb[(quad * 8) ^ sw];
            bf16x8 kf1 = *(const bf16x8*)&kb[(quad * 8 + 32) ^ sw];
            f32x4 acc = {0.f, 0.f, 0.f, 0.f};
            acc = __builtin_amdgcn_mfma_f32_16x16x32_bf16(qf[0], kf0, acc, 0, 0, 0);
            acc = __builtin_amdgcn_mfma_f32_16x16x32_bf16(qf[1], kf1, acc, 0, 0, 0);
            const int mv = msh[row];
            #pragma unroll
            for (int i = 0; i < 4; ++i) {
                float p = (mv == 1) ? 0.f : __expf(acc[i] * 0.125f);
                rsum[i] += p;
            }
        }
    }
    #pragma unroll
    for (int off = 1; off < 16; off <<= 1) {
        #pragma unroll
        for (int i = 0; i < 4; ++i) rsum[i] += __shfl_xor(rsum[i], off);
    }
    float rinv[4];
    #pragma unroll
    for (int i = 0; i < 4; ++i) rinv[i] = 1.0f / rsum[i];

    // ================= PASS 2: weights write + PV accumulate =================
    f32x4 oacc[4];
    #pragma unroll
    for (int nt = 0; nt < 4; ++nt) oacc[nt] = (f32x4){0.f, 0.f, 0.f, 0.f};

    float* pw = Pf[wave];
    for (int tt = 0; tt < NTILE; ++tt) {
        __syncthreads();
        const short* ks = kb_head + (size_t)tt * TILE_SH;
        const short* vs = vb_head + (size_t)tt * TILE_SH;
        gll16(ks + tid * 8,        &Ksh[wave * 512]);
        gll16(ks + 2048 + tid * 8, &Ksh[2048 + wave * 512]);
        gll16(vs + tid * 8,        &Vsh[wave * 512]);
        gll16(vs + 2048 + tid * 8, &Vsh[2048 + wave * 512]);
        if (tid < 64) msh[tid] = mk[tt * 64 + tid];
        __syncthreads();

        // QK^T + mask + exp + normalize; P (fp32) into per-wave LDS
        #pragma unroll
        for (int sub = 0; sub < 4; ++sub) {
            const int row = sub * 16 + col;
            const short* kb = &Ksh[row * 64];
            const int sw = (row & 7) * 8;
            bf16x8 kf0 = *(const bf16x8*)&kb[(quad * 8) ^ sw];
            bf16x8 kf1 = *(const bf16x8*)&kb[(quad * 8 + 32) ^ sw];
            f32x4 acc = {0.f, 0.f, 0.f, 0.f};
            acc = __builtin_amdgcn_mfma_f32_16x16x32_bf16(qf[0], kf0, acc, 0, 0, 0);
            acc = __builtin_amdgcn_mfma_f32_16x16x32_bf16(qf[1], kf1, acc, 0, 0, 0);
            const int mv = msh[row];
            #pragma unroll
            for (int i = 0; i < 4; ++i) {
                float p = (mv == 1) ? 0.f : __expf(acc[i] * 0.125f) * rinv[i];
                pw[(quad * 4 + i) * 68 + row] = p;   // C-layout: row=quad*4+i, col=key
            }
        }
        __syncthreads();   // cross-lane P visibility (cheap; also orders Vsh reuse)

        // W store: coalesced float4, 4 rows x 64 cols per iteration
        #pragma unroll
        for (int it = 0; it < 4; ++it) {
            const int r = it * 4 + quad;
            f32x4 pv = *(const f32x4*)&pw[r * 68 + col * 4];
            *(f32x4*)&wh[(size_t)(q0 + r) * S_ + tt * 64 + col * 4] = pv;
        }

        // PV: A = P (read fp32, pack bf16), B = V^T from swizzled LDS
        #pragma unroll
        for (int c = 0; c < 2; ++c) {
            const float* pr = &pw[col * 68 + c * 32 + quad * 8];
            f32x4 p0 = *(const f32x4*)pr;
            f32x4 p1 = *(const f32x4*)(pr + 4);
            bf16x8 af;
            af[0]=f2bf(p0[0]); af[1]=f2bf(p0[1]); af[2]=f2bf(p0[2]); af[3]=f2bf(p0[3]);
            af[4]=f2bf(p1[0]); af[5]=f2bf(p1[1]); af[6]=f2bf(p1[2]); af[7]=f2bf(p1[3]);
            const int ko = c * 32 + quad * 8;
            #pragma unroll
            for (int nt = 0; nt < 4; ++nt) {
                const int dr = nt * 16 + col;
                bf16x8 vf = *(const bf16x8*)&Vsh[dr * 64 + (ko ^ ((dr & 7) * 8))];
                oacc[nt] = __builtin_amdgcn_mfma_f32_16x16x32_bf16(af, vf, oacc[nt], 0, 0, 0);
            }
        }
    }

    // epilogue: O already normalized
    #pragma unroll
    for (int nt = 0; nt < 4; ++nt) {
        #pragma unroll
        for (int i = 0; i < 4; ++i)
            outh[(size_t)(q0 + quad * 4 + i) * D_ + nt * 16 + col] = oacc[nt][i];
    }
}

// ===================== fallback (previous verified kernel) ===================
__global__ __launch_bounds__(256, 2)
void attn_kernel(const float* __restrict__ Q, const float* __restrict__ K,
                 const float* __restrict__ V, const int* __restrict__ mask,
                 float* __restrict__ out, float* __restrict__ wout)
{
    __shared__ __align__(16) short Ksh[64 * KS];
    __shared__ __align__(16) short Vsh[64 * KS];
    __shared__ __align__(16) short Psh[4][16 * PS];
    __shared__ int msh[64];

    const int tid  = threadIdx.x;
    const int wave = tid >> 6;
    const int lane = tid & 63;
    const int quad = lane >> 4;
    const int col  = lane & 15;

    const int bh = blockIdx.x >> 5;
    const int qt = blockIdx.x & 31;
    const int q0 = qt * 64 + wave * 16;

    const float* Qh = Q + (size_t)bh * S_ * D_;
    const float* Kh = K + (size_t)bh * S_ * D_;
    const float* Vh = V + (size_t)bh * S_ * D_;
    const int*   mk = mask + (size_t)(bh >> 4) * S_;
    float* outh = out  + (size_t)bh * S_ * D_;
    float* wh   = wout + (size_t)bh * S_ * S_;

    bf16x8 qf[2];
    {
        const float* qp = Qh + (size_t)(q0 + col) * D_ + quad * 8;
        #pragma unroll
        for (int c = 0; c < 2; ++c) {
            bf16x8 v;
            #pragma unroll
            for (int j = 0; j < 8; ++j) v[j] = f2bf(qp[c * 32 + j]);
            qf[c] = v;
        }
    }

    const int srow = tid >> 2;
    const int sd0  = (tid & 3) * 16;

    float rsum[4] = {0.f, 0.f, 0.f, 0.f};
    for (int kt = 0; kt < S_; kt += 64) {
        __syncthreads();
        {
            const float4* kp4 = (const float4*)(Kh + (size_t)(kt + srow) * D_ + sd0);
            float4 a = kp4[0], b = kp4[1], c = kp4[2], d = kp4[3];
            bf16x8 lo, hi;
            lo[0]=f2bf(a.x); lo[1]=f2bf(a.y); lo[2]=f2bf(a.z); lo[3]=f2bf(a.w);
            lo[4]=f2bf(b.x); lo[5]=f2bf(b.y); lo[6]=f2bf(b.z); lo[7]=f2bf(b.w);
            hi[0]=f2bf(c.x); hi[1]=f2bf(c.y); hi[2]=f2bf(c.z); hi[3]=f2bf(c.w);
            hi[4]=f2bf(d.x); hi[5]=f2bf(d.y); hi[6]=f2bf(d.z); hi[7]=f2bf(d.w);
            *(bf16x8*)&Ksh[srow * KS + sd0]     = lo;
            *(bf16x8*)&Ksh[srow * KS + sd0 + 8] = hi;
            if (tid < 64) msh[tid] = mk[kt + tid];
        }
        __syncthreads();
        #pragma unroll
        for (int sub = 0; sub < 4; ++sub) {
            const short* kb = &Ksh[(sub * 16 + col) * KS + quad * 8];
            bf16x8 kf0 = *(const bf16x8*)kb;
            bf16x8 kf1 = *(const bf16x8*)(kb + 32);
            f32x4 acc = {0.f, 0.f, 0.f, 0.f};
            acc = __builtin_amdgcn_mfma_f32_16x16x32_bf16(qf[0], kf0, acc, 0, 0, 0);
            acc = __builtin_amdgcn_mfma_f32_16x16x32_bf16(qf[1], kf1, acc, 0, 0, 0);
            const int mv = msh[sub * 16 + col];
            #pragma unroll
            for (int i = 0; i < 4; ++i) {
                float p = (mv == 1) ? 0.f : __expf(acc[i] * 0.125f);
                rsum[i] += p;
            }
        }
    }
    #pragma unroll
    for (int off = 1; off < 16; off <<= 1) {
        #pragma unroll
        for (int i = 0; i < 4; ++i) rsum[i] += __shfl_xor(rsum[i], off);
    }
    float rinv[4];
    #pragma unroll
    for (int i = 0; i < 4; ++i) rinv[i] = 1.0f / rsum[i];

    f32x4 oacc[4];
    #pragma unroll
    for (int nt = 0; nt < 4; ++nt) oacc[nt] = (f32x4){0.f, 0.f, 0.f, 0.f};

    short* pw = Psh[wave];
    for (int kt = 0; kt < S_; kt += 64) {
        __syncthreads();
        {
            const float4* kp4 = (const float4*)(Kh + (size_t)(kt + srow) * D_ + sd0);
            float4 a = kp4[0], b = kp4[1], c = kp4[2], d = kp4[3];
            bf16x8 lo, hi;
            lo[0]=f2bf(a.x); lo[1]=f2bf(a.y); lo[2]=f2bf(a.z); lo[3]=f2bf(a.w);
            lo[4]=f2bf(b.x); lo[5]=f2bf(b.y); lo[6]=f2bf(b.z); lo[7]=f2bf(b.w);
            hi[0]=f2bf(c.x); hi[1]=f2bf(c.y); hi[2]=f2bf(c.z); hi[3]=f2bf(c.w);
            hi[4]=f2bf(d.x); hi[5]=f2bf(d.y); hi[6]=f2bf(d.z); hi[7]=f2bf(d.w);
            *(bf16x8*)&Ksh[srow * KS + sd0]     = lo;
            *(bf16x8*)&Ksh[srow * KS + sd0 + 8] = hi;

            const float4* vp4 = (const float4*)(Vh + (size_t)(kt + srow) * D_ + sd0);
            float4 va = vp4[0], vb = vp4[1], vc = vp4[2], vd = vp4[3];
            float vv[16] = {va.x, va.y, va.z, va.w, vb.x, vb.y, vb.z, vb.w,
                            vc.x, vc.y, vc.z, vc.w, vd.x, vd.y, vd.z, vd.w};
            #pragma unroll
            for (int j = 0; j < 16; ++j)
                Vsh[(sd0 + j) * KS + srow] = f2bf(vv[j]);

            if (tid < 64) msh[tid] = mk[kt + tid];
        }
        __syncthreads();
        #pragma unroll
        for (int sub = 0; sub < 4; ++sub) {
            const short* kb = &Ksh[(sub * 16 + col) * KS + quad * 8];
            bf16x8 kf0 = *(const bf16x8*)kb;
            bf16x8 kf1 = *(const bf16x8*)(kb + 32);
            f32x4 acc = {0.f, 0.f, 0.f, 0.f};
            acc = __builtin_amdgcn_mfma_f32_16x16x32_bf16(qf[0], kf0, acc, 0, 0, 0);
            acc = __builtin_amdgcn_mfma_f32_16x16x32_bf16(qf[1], kf1, acc, 0, 0, 0);
            const int mv = msh[sub * 16 + col];
            #pragma unroll
            for (int i = 0; i < 4; ++i) {
                float p = (mv == 1) ? 0.f : __expf(acc[i] * 0.125f) * rinv[i];
                wh[(size_t)(q0 + quad * 4 + i) * S_ + kt + sub * 16 + col] = p;
                pw[(quad * 4 + i) * PS + sub * 16 + col] = f2bf(p);
            }
        }
        __syncthreads();
        #pragma unroll
        for (int c = 0; c < 2; ++c) {
            bf16x8 af = *(const bf16x8*)&pw[col * PS + c * 32 + quad * 8];
            #pragma unroll
            for (int nt = 0; nt < 4; ++nt) {
                bf16x8 vf = *(const bf16x8*)&Vsh[(nt * 16 + col) * KS + c * 32 + quad * 8];
                oacc[nt] = __builtin_amdgcn_mfma_f32_16x16x32_bf16(af, vf, oacc[nt], 0, 0, 0);
            }
        }
    }

    #pragma unroll
    for (int nt = 0; nt < 4; ++nt) {
        #pragma unroll
        for (int i = 0; i < 4; ++i)
            outh[(size_t)(q0 + quad * 4 + i) * D_ + nt * 16 + col] = oacc[nt][i];
    }
}

extern "C" void kernel_launch(void* const* d_in, const int* in_sizes, int n_in,
                              void* d_out, int out_size, void* d_ws, size_t ws_size,
                              hipStream_t stream) {
    const float* Q    = (const float*)d_in[0];
    const float* K    = (const float*)d_in[1];
    const float* V    = (const float*)d_in[2];
    const int*   mask = (const int*)d_in[3];
    float* out  = (float*)d_out;
    float* wout = out + (size_t)B_ * H_ * S_ * D_;

    const size_t scratch_need = (size_t)2 * NHEAD * HEAD_SH * sizeof(short); // 33.55 MB
    if (d_ws && ws_size >= scratch_need) {
        short* kscr = (short*)d_ws;
        short* vscr = kscr + (size_t)NHEAD * HEAD_SH;
        const int nchunks = 2 * NHEAD * S_ * (D_ / 8);     // K + V 16B chunks
        prep_kernel<<<nchunks / 256, 256, 0, stream>>>(K, V, kscr, vscr);
        attn2_kernel<<<B_ * H_ * S_ / 64, 256, 0, stream>>>(Q, mask, kscr, vscr, out, wout);
    } else {
        attn_kernel<<<B_ * H_ * S_ / 64, 256, 0, stream>>>(Q, K, V, mask, out, wout);
    }
}